// Round 4
// baseline (1788.423 us; speedup 1.0000x reference)
//
#include <hip/hip_runtime.h>
#include <math.h>

typedef short bf16x8 __attribute__((ext_vector_type(8)));
typedef float f32x4 __attribute__((ext_vector_type(4)));

static __device__ __forceinline__ float wred_sum(float v){
  #pragma unroll
  for (int o = 32; o > 0; o >>= 1) v += __shfl_xor(v, o, 64);
  return v;
}

static __device__ __forceinline__ float wred_max(float v){
  #pragma unroll
  for (int o = 32; o > 0; o >>= 1) v = fmaxf(v, __shfl_xor(v, o, 64));
  return v;
}

static __device__ __forceinline__ unsigned short f2bf(float x){
  union { float f; unsigned int u; } c; c.f = x;
  unsigned int u = c.u;
  return (unsigned short)((u + 0x7FFFu + ((u >> 16) & 1u)) >> 16);
}

static __device__ __forceinline__ float b2f(unsigned short x){
  union { unsigned int u; float f; } c; c.u = ((unsigned int)x) << 16;
  return c.f;
}

// ---------------- prep ----------------
__global__ void prep_kernel(const float* __restrict__ x, const float* __restrict__ ea_in,
                            float* __restrict__ hx, float* __restrict__ ea,
                            int nx, int ne){
  int i = blockIdx.x * 256 + threadIdx.x;
  if (i < nx) hx[i] = logf(x[i] + 1.f);
  if (i < ne) ea[i] = logf(ea_in[i] + 1.f);
}

// ---------------- CSR build ----------------
__global__ void zero_kernel(int* __restrict__ c, int n){
  int i = blockIdx.x * 256 + threadIdx.x;
  if (i < n) c[i] = 0;
}

__global__ void hist_kernel(const int* __restrict__ dst, int* __restrict__ counts, int E){
  int i = blockIdx.x * 256 + threadIdx.x;
  if (i < E) atomicAdd(&counts[dst[i]], 1);
}

__global__ __launch_bounds__(1024) void scan_kernel(const int* __restrict__ counts,
                                                    int* __restrict__ row_ptr,
                                                    int* __restrict__ cursor, int N){
  __shared__ int sh[1024];
  __shared__ int carry_s;
  int t = threadIdx.x;
  if (t == 0) carry_s = 0;
  __syncthreads();
  for (int base = 0; base < N; base += 1024){
    int i = base + t;
    int v = (i < N) ? counts[i] : 0;
    sh[t] = v;
    __syncthreads();
    for (int o = 1; o < 1024; o <<= 1){
      int add = (t >= o) ? sh[t - o] : 0;
      __syncthreads();
      sh[t] += add;
      __syncthreads();
    }
    int incl = sh[t];
    int carry = carry_s;
    if (i < N){ int ex = carry + incl - v; row_ptr[i] = ex; cursor[i] = ex; }
    __syncthreads();
    if (t == 1023) carry_s = carry + incl;
    __syncthreads();
  }
  if (t == 0) row_ptr[N] = carry_s;
}

__global__ void scatter_kernel(const int* __restrict__ dst, int* __restrict__ cursor,
                               int* __restrict__ eids, int E){
  int i = blockIdx.x * 256 + threadIdx.x;
  if (i < E){
    int pos = atomicAdd(&cursor[dst[i]], 1);
    eids[pos] = i;
  }
}

// ---------------- head helper ----------------
__global__ void wlscale_kernel(const float* __restrict__ Wl, const float* __restrict__ bl,
                               const float* __restrict__ scale, float* __restrict__ wlsc){
  int c = threadIdx.x;
  float s = 0.f;
  #pragma unroll
  for (int j = 0; j < 8; j++) s += Wl[c * 8 + j] * scale[j];
  wlsc[c] = s;
  if (c == 0){
    float b = 0.f;
    #pragma unroll
    for (int j = 0; j < 8; j++) b += bl[j] * scale[j];
    wlsc[256] = b;
  }
}

// ---------------- weight pack: Wp[l][ncat][k] = W(l)[k][n] bf16 ----------------
__global__ __launch_bounds__(256) void pack_w_kernel(
    const float* __restrict__ Wq, const float* __restrict__ Wk,
    const float* __restrict__ Wv, const float* __restrict__ Ws,
    unsigned short* __restrict__ Wp)
{
  __shared__ float t[32][33];
  int l   = blockIdx.z;
  int k0  = blockIdx.x * 32;
  int n0g = blockIdx.y * 32;
  int w   = n0g >> 8;
  int n0  = n0g & 255;
  const float* W = ((w == 0) ? Wq : (w == 1) ? Wk : (w == 2) ? Wv : Ws) + (size_t)l * 65536;
  int rr = threadIdx.x >> 3;
  int cc = (threadIdx.x & 7) * 4;
  float4 vv = *(const float4*)&W[(size_t)(k0 + rr) * 256 + n0 + cc];
  t[rr][cc + 0] = vv.x; t[rr][cc + 1] = vv.y; t[rr][cc + 2] = vv.z; t[rr][cc + 3] = vv.w;
  __syncthreads();
  ushort4 o;
  o.x = f2bf(t[cc + 0][rr]);
  o.y = f2bf(t[cc + 1][rr]);
  o.z = f2bf(t[cc + 2][rr]);
  o.w = f2bf(t[cc + 3][rr]);
  *(ushort4*)&Wp[(size_t)l * 262144 + (size_t)(n0g + rr) * 256 + k0 + cc] = o;
}

__global__ void pack_b_kernel(const float* __restrict__ bq, const float* __restrict__ bk,
                              const float* __restrict__ bv, const float* __restrict__ bs,
                              float* __restrict__ bp){
  int i = blockIdx.x * 256 + threadIdx.x;
  if (i < 15 * 256){
    int l = i >> 8, n = i & 255;
    bp[l * 1024 + 0   + n] = bq[i];
    bp[l * 1024 + 256 + n] = bk[i];
    bp[l * 1024 + 512 + n] = bv[i];
    bp[l * 1024 + 768 + n] = bs[i];
  }
}

// ---------------- pack Wqe[l][c][j] = sum_d Wq[l][c][d]*We[l][j][d]; bqe --------
__global__ __launch_bounds__(256) void pack_wqe_kernel(
    const float* __restrict__ Wq, const float* __restrict__ We,
    const float* __restrict__ bq, float* __restrict__ Wqe, float* __restrict__ bqe)
{
  __shared__ float We_s[1024];
  int l = blockIdx.x;
  for (int i = threadIdx.x; i < 1024; i += 256) We_s[i] = We[(size_t)l * 1024 + i];
  __syncthreads();
  int k = threadIdx.x;
  const float* wrow = Wq + (size_t)l * 65536 + (size_t)k * 256;
  float s0 = 0.f, s1 = 0.f, s2 = 0.f, s3 = 0.f;
  for (int c = 0; c < 256; c++){
    float wv = wrow[c];
    s0 += wv * We_s[c];
    s1 += wv * We_s[256 + c];
    s2 += wv * We_s[512 + c];
    s3 += wv * We_s[768 + c];
  }
  float4 o; o.x = s0; o.y = s1; o.z = s2; o.w = s3;
  *(float4*)&Wqe[((size_t)l * 256 + k) * 4] = o;
  if (k < 4){
    float b = 0.f;
    for (int c = 0; c < 256; c++) b += bq[l * 256 + c] * We_s[k * 256 + c];
    bqe[l * 4 + k] = b;
  }
}

// ---------------- qwe for conv1: qwe[n][j] = sum_c q1[n,c]*We1[j,c] ----------------
__global__ __launch_bounds__(256) void qwe1_kernel(const unsigned short* __restrict__ qkvb,
                                                   const float* __restrict__ We1,
                                                   float* __restrict__ qwe, int N){
  __shared__ float We_s[1024];
  for (int i = threadIdx.x; i < 1024; i += 256) We_s[i] = We1[i];
  __syncthreads();
  int wid = threadIdx.x >> 6, lane = threadIdx.x & 63;
  int n = blockIdx.x * 4 + wid;
  if (n >= N) return;
  int c0 = lane * 4;
  ushort4 qr = *(const ushort4*)&qkvb[(size_t)n * 768 + c0];
  float q0 = b2f(qr.x), q1 = b2f(qr.y), q2 = b2f(qr.z), q3 = b2f(qr.w);
  float4 o;
  #pragma unroll
  for (int j = 0; j < 4; j++){
    float s = q0 * We_s[j * 256 + c0] + q1 * We_s[j * 256 + c0 + 1]
            + q2 * We_s[j * 256 + c0 + 2] + q3 * We_s[j * 256 + c0 + 3];
    s = wred_sum(s);
    if (j == 0) o.x = s; else if (j == 1) o.y = s; else if (j == 2) o.z = s; else o.w = s;
  }
  if (lane == 0) *(float4*)&qwe[(size_t)n * 4] = o;
}

// ---------------- conv1 GEMMs ----------------
__global__ __launch_bounds__(256) void gemm1_kernel(
    const float* __restrict__ A,
    const float* __restrict__ W0, const float* __restrict__ W1,
    const float* __restrict__ W2, const float* __restrict__ W3,
    const float* __restrict__ B0, const float* __restrict__ B1,
    const float* __restrict__ B2, const float* __restrict__ B3,
    unsigned short* __restrict__ qkvb, float* __restrict__ sl, int N)
{
  __shared__ float As[64][16];
  int nb = blockIdx.x * 64;
  {
    int row = nb + (threadIdx.x >> 2);
    int qq = (threadIdx.x & 3) * 4;
    float4 a = make_float4(0.f, 0.f, 0.f, 0.f);
    if (row < N) a = *(const float4*)&A[row * 16 + qq];
    *(float4*)&As[threadIdx.x >> 2][qq] = a;
  }
  __syncthreads();
  int col = threadIdx.x;
  #pragma unroll
  for (int w = 0; w < 4; w++){
    const float* W  = (w == 0) ? W0 : (w == 1) ? W1 : (w == 2) ? W2 : W3;
    const float* Bi = (w == 0) ? B0 : (w == 1) ? B1 : (w == 2) ? B2 : B3;
    float wr[16];
    #pragma unroll
    for (int kk = 0; kk < 16; kk++) wr[kk] = W[kk * 256 + col];
    float bias = Bi[col];
    for (int r = 0; r < 64; r++){
      int row = nb + r;
      if (row >= N) break;
      float acc = bias;
      #pragma unroll
      for (int kk = 0; kk < 16; kk++) acc += As[r][kk] * wr[kk];
      if (w < 3) qkvb[(size_t)row * 768 + w * 256 + col] = f2bf(acc);
      else       sl[(size_t)row * 256 + col] = acc;
    }
  }
}

// ---------------- main MFMA GEMM ----------------
__global__ __launch_bounds__(256, 2) void gemm_mfma_kernel(
    const unsigned short* __restrict__ A,
    const unsigned short* __restrict__ Wp,
    const float* __restrict__ bp,
    unsigned short* __restrict__ qkvb,
    float* __restrict__ sl,
    int M)
{
  __shared__ unsigned short lds[2 * 128 * 64];
  unsigned short* ldsA = lds;
  unsigned short* ldsB = lds + 128 * 64;
  const int tid  = threadIdx.x;
  const int wave = tid >> 6, lane = tid & 63;
  const int wm = wave >> 1, wn = wave & 1;
  const int m0 = blockIdx.x * 128;
  const int n0 = blockIdx.y * 128;

  f32x4 acc[4][4] = {};

  const int srow  = lane >> 3;
  const int sc16  = lane & 7;
  const int skgrp = sc16 ^ (srow & 7);

  for (int k0 = 0; k0 < 256; k0 += 64){
    #pragma unroll
    for (int it = 0; it < 4; ++it){
      int lrow = wave * 32 + it * 8;
      const unsigned short* gA = A + (size_t)(m0 + lrow + srow) * 256 + k0 + skgrp * 8;
      __builtin_amdgcn_global_load_lds((const __attribute__((address_space(1))) unsigned int*)gA,
          (__attribute__((address_space(3))) unsigned int*)(ldsA + lrow * 64), 16, 0, 0);
      const unsigned short* gB = Wp + (size_t)(n0 + lrow + srow) * 256 + k0 + skgrp * 8;
      __builtin_amdgcn_global_load_lds((const __attribute__((address_space(1))) unsigned int*)gB,
          (__attribute__((address_space(3))) unsigned int*)(ldsB + lrow * 64), 16, 0, 0);
    }
    __syncthreads();

    bf16x8 af[4][2], bfr[4][2];
    #pragma unroll
    for (int mb = 0; mb < 4; ++mb){
      int r = wm * 64 + mb * 16 + (lane & 15);
      #pragma unroll
      for (int ks = 0; ks < 2; ++ks){
        int kg = ks * 4 + (lane >> 4);
        af[mb][ks] = *(const bf16x8*)&ldsA[r * 64 + ((kg ^ (r & 7)) * 8)];
      }
    }
    #pragma unroll
    for (int nb = 0; nb < 4; ++nb){
      int r = wn * 64 + nb * 16 + (lane & 15);
      #pragma unroll
      for (int ks = 0; ks < 2; ++ks){
        int kg = ks * 4 + (lane >> 4);
        bfr[nb][ks] = *(const bf16x8*)&ldsB[r * 64 + ((kg ^ (r & 7)) * 8)];
      }
    }
    #pragma unroll
    for (int mb = 0; mb < 4; ++mb){
      #pragma unroll
      for (int nb = 0; nb < 4; ++nb){
        acc[mb][nb] = __builtin_amdgcn_mfma_f32_16x16x32_bf16(af[mb][0], bfr[nb][0], acc[mb][nb], 0, 0, 0);
        acc[mb][nb] = __builtin_amdgcn_mfma_f32_16x16x32_bf16(af[mb][1], bfr[nb][1], acc[mb][nb], 0, 0, 0);
      }
    }
    __syncthreads();
  }

  #pragma unroll
  for (int nb = 0; nb < 4; ++nb){
    int col = n0 + wn * 64 + nb * 16 + (lane & 15);
    float bias = bp[col];
    #pragma unroll
    for (int mb = 0; mb < 4; ++mb){
      #pragma unroll
      for (int r4 = 0; r4 < 4; ++r4){
        int row = m0 + wm * 64 + mb * 16 + (lane >> 4) * 4 + r4;
        if (row < M){
          float o = acc[mb][nb][r4] + bias;
          if (col < 768) qkvb[(size_t)row * 768 + col] = f2bf(o);
          else           sl[(size_t)row * 256 + (col - 768)] = o;
        }
      }
    }
  }
}

// ---------------- attention aggregation (two-phase, We folded out) ----------------
__global__ __launch_bounds__(256) void agg_kernel(
    const unsigned short* __restrict__ qkvb,  // [N][768] bf16 q|k|v
    const float* __restrict__ sl,             // [N][256]
    const float* __restrict__ qwe,            // [N][4]
    const float* __restrict__ ea,             // [E][4]
    const float* __restrict__ We,             // [4][256] this layer (v-side epilogue)
    const float* __restrict__ Wqe_next,       // [256][4] or null
    const float* __restrict__ bqe_next,       // [4] or null
    const int* __restrict__ src, const int* __restrict__ row_ptr,
    const int* __restrict__ eids,
    const float* __restrict__ h_in, float* __restrict__ h_out,
    unsigned short* __restrict__ h2b, float* __restrict__ qwe_out,
    int RESID, int N)
{
  __shared__ float We_s[1024];
  __shared__ float Wqe_s[1024];
  for (int i = threadIdx.x; i < 1024; i += 256) We_s[i] = We[i];
  if (Wqe_next)
    for (int i = threadIdx.x; i < 1024; i += 256) Wqe_s[i] = Wqe_next[i];
  __syncthreads();
  int wid = threadIdx.x >> 6, lane = threadIdx.x & 63;
  int n = blockIdx.x * 4 + wid;
  if (n >= N) return;
  int c0 = lane * 4;

  ushort4 qr = *(const ushort4*)&qkvb[(size_t)n * 768 + c0];
  float qx = b2f(qr.x), qy = b2f(qr.y), qz = b2f(qr.z), qw = b2f(qr.w);
  float4 qwe4 = *(const float4*)&qwe[(size_t)n * 4];

  float m = -INFINITY, ssum = 0.f;
  float a0 = 0.f, a1 = 0.f, a2 = 0.f, a3 = 0.f;
  float ec0 = 0.f, ec1 = 0.f, ec2 = 0.f, ec3 = 0.f;
  int e0 = row_ptr[n], e1 = row_ptr[n + 1];

  for (int base = e0; base < e1; base += 64){
    int cnt = min(64, e1 - base);
    // ---- phase 1: alphas (independent iterations) ----
    float my_alpha = -INFINITY;
    int s_n; float4 ea_n; ushort4 k_n;
    {
      int e = eids[base];
      s_n = src[e];
      ea_n = *(const float4*)&ea[e * 4];
      k_n = *(const ushort4*)&qkvb[(size_t)s_n * 768 + 256 + c0];
    }
    for (int i = 0; i < cnt; ++i){
      float4 eav = ea_n; ushort4 kr = k_n;
      if (i + 1 < cnt){
        int e = eids[base + i + 1];
        s_n = src[e];
        ea_n = *(const float4*)&ea[e * 4];
        k_n = *(const ushort4*)&qkvb[(size_t)s_n * 768 + 256 + c0];
      }
      float part = qx * b2f(kr.x) + qy * b2f(kr.y) + qz * b2f(kr.z) + qw * b2f(kr.w);
      part = wred_sum(part);
      float edot = qwe4.x * eav.x + qwe4.y * eav.y + qwe4.z * eav.z + qwe4.w * eav.w;
      float alpha = (part + edot) * 0.0625f;
      my_alpha = (lane == i) ? alpha : my_alpha;
    }
    // ---- chunk softmax merge ----
    float mc = wred_max(my_alpha);
    float mn = fmaxf(m, mc);
    float corr = expf(m - mn);           // m=-inf on first chunk -> 0
    float w = (lane < cnt) ? expf(my_alpha - mn) : 0.f;
    ssum = ssum * corr + wred_sum(w);
    a0 *= corr; a1 *= corr; a2 *= corr; a3 *= corr;
    ec0 *= corr; ec1 *= corr; ec2 *= corr; ec3 *= corr;
    m = mn;
    // ---- phase 2: weighted gather (independent FMA chain) ----
    float4 ea2_n; ushort4 v_n;
    {
      int e = eids[base];
      int s = src[e];
      ea2_n = *(const float4*)&ea[e * 4];
      v_n = *(const ushort4*)&qkvb[(size_t)s * 768 + 512 + c0];
    }
    for (int i = 0; i < cnt; ++i){
      float4 eav = ea2_n; ushort4 vr = v_n;
      if (i + 1 < cnt){
        int e = eids[base + i + 1];
        int s = src[e];
        ea2_n = *(const float4*)&ea[e * 4];
        v_n = *(const ushort4*)&qkvb[(size_t)s * 768 + 512 + c0];
      }
      float aw = __shfl(w, i, 64);
      a0 += aw * b2f(vr.x);
      a1 += aw * b2f(vr.y);
      a2 += aw * b2f(vr.z);
      a3 += aw * b2f(vr.w);
      ec0 += aw * eav.x;
      ec1 += aw * eav.y;
      ec2 += aw * eav.z;
      ec3 += aw * eav.w;
    }
  }

  float inv = 1.f / (ssum + 1e-16f);
  // v-side edge embedding: emb_c = sum_j ec_j * We[j][c]
  float emb0 = ec0 * We_s[c0 + 0] + ec1 * We_s[256 + c0 + 0] + ec2 * We_s[512 + c0 + 0] + ec3 * We_s[768 + c0 + 0];
  float emb1 = ec0 * We_s[c0 + 1] + ec1 * We_s[256 + c0 + 1] + ec2 * We_s[512 + c0 + 1] + ec3 * We_s[768 + c0 + 1];
  float emb2 = ec0 * We_s[c0 + 2] + ec1 * We_s[256 + c0 + 2] + ec2 * We_s[512 + c0 + 2] + ec3 * We_s[768 + c0 + 2];
  float emb3 = ec0 * We_s[c0 + 3] + ec1 * We_s[256 + c0 + 3] + ec2 * We_s[512 + c0 + 3] + ec3 * We_s[768 + c0 + 3];
  float4 slv = *(const float4*)&sl[(size_t)n * 256 + c0];
  float y0 = (a0 + emb0) * inv + slv.x;
  float y1 = (a1 + emb1) * inv + slv.y;
  float y2 = (a2 + emb2) * inv + slv.z;
  float y3 = (a3 + emb3) * inv + slv.w;
  float o0, o1, o2, o3;
  if (RESID){
    float4 hp = *(const float4*)&h_in[(size_t)n * 256 + c0];
    o0 = hp.x + y0; o1 = hp.y + y1; o2 = hp.z + y2; o3 = hp.w + y3;
  } else {
    o0 = y0; o1 = y1; o2 = y2; o3 = y3;
  }
  float4 ho; ho.x = o0; ho.y = o1; ho.z = o2; ho.w = o3;
  *(float4*)&h_out[(size_t)n * 256 + c0] = ho;
  float mean = wred_sum(o0 + o1 + o2 + o3) * (1.f / 256.f);
  float d0 = o0 - mean, d1 = o1 - mean, d2 = o2 - mean, d3 = o3 - mean;
  float var = wred_sum(d0 * d0 + d1 * d1 + d2 * d2 + d3 * d3) * (1.f / 255.f);
  float invstd = 1.f / sqrtf(var);
  float t0 = fmaxf(o0 * invstd, 0.f);
  float t1 = fmaxf(o1 * invstd, 0.f);
  float t2 = fmaxf(o2 * invstd, 0.f);
  float t3 = fmaxf(o3 * invstd, 0.f);
  ushort4 hb;
  hb.x = f2bf(t0); hb.y = f2bf(t1); hb.z = f2bf(t2); hb.w = f2bf(t3);
  *(ushort4*)&h2b[(size_t)n * 256 + c0] = hb;
  // chain: qwe for NEXT layer = h2 @ Wqe_next + bqe_next
  if (Wqe_next){
    float4 o;
    #pragma unroll
    for (int j = 0; j < 4; j++){
      float s = t0 * Wqe_s[(c0 + 0) * 4 + j] + t1 * Wqe_s[(c0 + 1) * 4 + j]
              + t2 * Wqe_s[(c0 + 2) * 4 + j] + t3 * Wqe_s[(c0 + 3) * 4 + j];
      s = wred_sum(s);
      if (j == 0) o.x = s; else if (j == 1) o.y = s; else if (j == 2) o.z = s; else o.w = s;
    }
    if (lane == 0){
      float4 bq4 = *(const float4*)bqe_next;
      o.x += bq4.x; o.y += bq4.y; o.z += bq4.z; o.w += bq4.w;
      *(float4*)&qwe_out[(size_t)n * 4] = o;
    }
  }
}

// ---------------- output head ----------------
__global__ __launch_bounds__(256) void head_kernel(const float* __restrict__ h,
                                                   const float* __restrict__ wlsc,
                                                   float* __restrict__ out, int N){
  int wid = threadIdx.x >> 6, lane = threadIdx.x & 63;
  int n = blockIdx.x * 4 + wid;
  if (n >= N) return;
  int c0 = lane * 4;
  float4 hv = *(const float4*)&h[(size_t)n * 256 + c0];
  float4 wv = *(const float4*)&wlsc[c0];
  float p = hv.x * wv.x + hv.y * wv.y + hv.z * wv.z + hv.w * wv.w;
  p = wred_sum(p);
  if (lane == 0) out[n] = p * (1.f / sqrtf(15.f)) + wlsc[256];
}

// ---------------- launch ----------------
extern "C" void kernel_launch(void* const* d_in, const int* in_sizes, int n_in,
                              void* d_out, int out_size, void* d_ws, size_t ws_size,
                              hipStream_t stream)
{
  const float* x     = (const float*)d_in[0];
  const int*   eidx  = (const int*)d_in[1];
  const float* Wq1 = (const float*)d_in[3];  const float* bq1 = (const float*)d_in[4];
  const float* Wk1 = (const float*)d_in[5];  const float* bk1 = (const float*)d_in[6];
  const float* Wv1 = (const float*)d_in[7];  const float* bv1 = (const float*)d_in[8];
  const float* We1 = (const float*)d_in[9];
  const float* Ws1 = (const float*)d_in[10]; const float* bs1 = (const float*)d_in[11];
  const float* Wq = (const float*)d_in[12];  const float* bq = (const float*)d_in[13];
  const float* Wk = (const float*)d_in[14];  const float* bk = (const float*)d_in[15];
  const float* Wv = (const float*)d_in[16];  const float* bv = (const float*)d_in[17];
  const float* We = (const float*)d_in[18];
  const float* Ws = (const float*)d_in[19];  const float* bs = (const float*)d_in[20];
  const float* Wl = (const float*)d_in[21];  const float* bl = (const float*)d_in[22];
  const float* scale = (const float*)d_in[23];
  (void)n_in; (void)ws_size;

  int N = in_sizes[0] / 16;
  int E = in_sizes[2] / 4;
  int Mpad = (N + 127) & ~127;
  float* out = (float*)d_out;
  (void)out_size;

  char* p = (char*)d_ws;
  auto alloc = [&](size_t bytes) -> char* {
    char* r = p; p += (bytes + 255) & ~(size_t)255; return r;
  };
  float* hx   = (float*)alloc((size_t)N * 16 * 4);
  float* ea   = (float*)alloc((size_t)E * 4 * 4);
  float* h    = (float*)alloc((size_t)N * 256 * 4);
  unsigned short* h2b = (unsigned short*)alloc((size_t)Mpad * 256 * 2);
  unsigned short* qkvb = (unsigned short*)alloc((size_t)N * 768 * 2);
  float* sl   = (float*)alloc((size_t)N * 256 * 4);
  float* qwe  = (float*)alloc((size_t)N * 4 * 4);
  unsigned short* Wp  = (unsigned short*)alloc((size_t)15 * 1024 * 256 * 2);
  float* bp   = (float*)alloc((size_t)15 * 1024 * 4);
  float* Wqe  = (float*)alloc((size_t)15 * 256 * 4 * 4);
  float* bqe  = (float*)alloc((size_t)15 * 4 * 4);
  float* wlsc = (float*)alloc(257 * 4);
  int* counts  = (int*)alloc((size_t)N * 4);
  int* cursor  = (int*)alloc((size_t)N * 4);
  int* row_ptr = (int*)alloc(((size_t)N + 1) * 4);
  int* eids    = (int*)alloc((size_t)E * 4);

  const int* srcp = eidx;
  const int* dstp = eidx + E;

  int nx = N * 16, ne = E * 4;
  int big = nx > ne ? nx : ne;

  zero_kernel<<<(N + 255) / 256, 256, 0, stream>>>(counts, N);
  prep_kernel<<<(big + 255) / 256, 256, 0, stream>>>(x, (const float*)d_in[2], hx, ea, nx, ne);
  hist_kernel<<<(E + 255) / 256, 256, 0, stream>>>(dstp, counts, E);
  scan_kernel<<<1, 1024, 0, stream>>>(counts, row_ptr, cursor, N);
  scatter_kernel<<<(E + 255) / 256, 256, 0, stream>>>(dstp, cursor, eids, E);
  wlscale_kernel<<<1, 256, 0, stream>>>(Wl, bl, scale, wlsc);
  pack_w_kernel<<<dim3(8, 32, 15), 256, 0, stream>>>(Wq, Wk, Wv, Ws, Wp);
  pack_b_kernel<<<15, 256, 0, stream>>>(bq, bk, bv, bs, bp);
  pack_wqe_kernel<<<15, 256, 0, stream>>>(Wq, We, bq, Wqe, bqe);

  // conv1
  gemm1_kernel<<<(N + 63) / 64, 256, 0, stream>>>(hx, Wq1, Wk1, Wv1, Ws1,
                                                  bq1, bk1, bv1, bs1, qkvb, sl, N);
  qwe1_kernel<<<(N + 3) / 4, 256, 0, stream>>>(qkvb, We1, qwe, N);
  agg_kernel<<<(N + 3) / 4, 256, 0, stream>>>(qkvb, sl, qwe, ea, We1,
                                              Wqe, bqe, srcp, row_ptr, eids,
                                              h, h, h2b, qwe, 0, N);

  // 15 residual blocks
  for (int l = 0; l < 15; l++){
    gemm_mfma_kernel<<<dim3(Mpad / 128, 8), 256, 0, stream>>>(
        h2b, Wp + (size_t)l * 262144, bp + (size_t)l * 1024, qkvb, sl, N);
    const float* wqe_n = (l < 14) ? (Wqe + (size_t)(l + 1) * 1024) : nullptr;
    const float* bqe_n = (l < 14) ? (bqe + (size_t)(l + 1) * 4) : nullptr;
    agg_kernel<<<(N + 3) / 4, 256, 0, stream>>>(qkvb, sl, qwe, ea, We + (size_t)l * 1024,
                                                wqe_n, bqe_n, srcp, row_ptr, eids,
                                                h, h, h2b, qwe, 1, N);
  }

  head_kernel<<<(N + 3) / 4, 256, 0, stream>>>(h, wlsc, out, N);
}

// Round 5
// 1424.837 us; speedup vs baseline: 1.2552x; 1.2552x over previous
//
#include <hip/hip_runtime.h>
#include <math.h>

typedef short bf16x8 __attribute__((ext_vector_type(8)));
typedef float f32x4 __attribute__((ext_vector_type(4)));

static __device__ __forceinline__ float wred_sum(float v){
  #pragma unroll
  for (int o = 32; o > 0; o >>= 1) v += __shfl_xor(v, o, 64);
  return v;
}

static __device__ __forceinline__ float wred_max(float v){
  #pragma unroll
  for (int o = 32; o > 0; o >>= 1) v = fmaxf(v, __shfl_xor(v, o, 64));
  return v;
}

static __device__ __forceinline__ unsigned short f2bf(float x){
  union { float f; unsigned int u; } c; c.f = x;
  unsigned int u = c.u;
  return (unsigned short)((u + 0x7FFFu + ((u >> 16) & 1u)) >> 16);
}

static __device__ __forceinline__ float b2f(unsigned short x){
  union { unsigned int u; float f; } c; c.u = ((unsigned int)x) << 16;
  return c.f;
}

// ---------------- prep ----------------
__global__ void prep_kernel(const float* __restrict__ x, const float* __restrict__ ea_in,
                            float* __restrict__ hx, float* __restrict__ ea,
                            int nx, int ne){
  int i = blockIdx.x * 256 + threadIdx.x;
  if (i < nx) hx[i] = logf(x[i] + 1.f);
  if (i < ne) ea[i] = logf(ea_in[i] + 1.f);
}

// ---------------- CSR build ----------------
__global__ void zero_kernel(int* __restrict__ c, int n){
  int i = blockIdx.x * 256 + threadIdx.x;
  if (i < n) c[i] = 0;
}

__global__ void hist_kernel(const int* __restrict__ dst, int* __restrict__ counts, int E){
  int i = blockIdx.x * 256 + threadIdx.x;
  if (i < E) atomicAdd(&counts[dst[i]], 1);
}

__global__ __launch_bounds__(1024) void scan_kernel(const int* __restrict__ counts,
                                                    int* __restrict__ row_ptr,
                                                    int* __restrict__ cursor, int N){
  __shared__ int sh[1024];
  __shared__ int carry_s;
  int t = threadIdx.x;
  if (t == 0) carry_s = 0;
  __syncthreads();
  for (int base = 0; base < N; base += 1024){
    int i = base + t;
    int v = (i < N) ? counts[i] : 0;
    sh[t] = v;
    __syncthreads();
    for (int o = 1; o < 1024; o <<= 1){
      int add = (t >= o) ? sh[t - o] : 0;
      __syncthreads();
      sh[t] += add;
      __syncthreads();
    }
    int incl = sh[t];
    int carry = carry_s;
    if (i < N){ int ex = carry + incl - v; row_ptr[i] = ex; cursor[i] = ex; }
    __syncthreads();
    if (t == 1023) carry_s = carry + incl;
    __syncthreads();
  }
  if (t == 0) row_ptr[N] = carry_s;
}

// scatter: also build CSR-ordered src/ea copies and the e->slot map
__global__ void scatter_kernel(const int* __restrict__ src, const int* __restrict__ dst,
                               const float* __restrict__ ea,
                               int* __restrict__ cursor, int* __restrict__ pos,
                               int* __restrict__ src_csr, float* __restrict__ ea_csr, int E){
  int i = blockIdx.x * 256 + threadIdx.x;
  if (i < E){
    int p = atomicAdd(&cursor[dst[i]], 1);
    pos[i] = p;
    src_csr[p] = src[i];
    *(float4*)&ea_csr[(size_t)p * 4] = *(const float4*)&ea[(size_t)i * 4];
  }
}

// ---------------- head helper ----------------
__global__ void wlscale_kernel(const float* __restrict__ Wl, const float* __restrict__ bl,
                               const float* __restrict__ scale, float* __restrict__ wlsc){
  int c = threadIdx.x;
  float s = 0.f;
  #pragma unroll
  for (int j = 0; j < 8; j++) s += Wl[c * 8 + j] * scale[j];
  wlsc[c] = s;
  if (c == 0){
    float b = 0.f;
    #pragma unroll
    for (int j = 0; j < 8; j++) b += bl[j] * scale[j];
    wlsc[256] = b;
  }
}

// ---------------- weight pack ----------------
__global__ __launch_bounds__(256) void pack_w_kernel(
    const float* __restrict__ Wq, const float* __restrict__ Wk,
    const float* __restrict__ Wv, const float* __restrict__ Ws,
    unsigned short* __restrict__ Wp)
{
  __shared__ float t[32][33];
  int l   = blockIdx.z;
  int k0  = blockIdx.x * 32;
  int n0g = blockIdx.y * 32;
  int w   = n0g >> 8;
  int n0  = n0g & 255;
  const float* W = ((w == 0) ? Wq : (w == 1) ? Wk : (w == 2) ? Wv : Ws) + (size_t)l * 65536;
  int rr = threadIdx.x >> 3;
  int cc = (threadIdx.x & 7) * 4;
  float4 vv = *(const float4*)&W[(size_t)(k0 + rr) * 256 + n0 + cc];
  t[rr][cc + 0] = vv.x; t[rr][cc + 1] = vv.y; t[rr][cc + 2] = vv.z; t[rr][cc + 3] = vv.w;
  __syncthreads();
  ushort4 o;
  o.x = f2bf(t[cc + 0][rr]);
  o.y = f2bf(t[cc + 1][rr]);
  o.z = f2bf(t[cc + 2][rr]);
  o.w = f2bf(t[cc + 3][rr]);
  *(ushort4*)&Wp[(size_t)l * 262144 + (size_t)(n0g + rr) * 256 + k0 + cc] = o;
}

__global__ void pack_b_kernel(const float* __restrict__ bq, const float* __restrict__ bk,
                              const float* __restrict__ bv, const float* __restrict__ bs,
                              float* __restrict__ bp){
  int i = blockIdx.x * 256 + threadIdx.x;
  if (i < 15 * 256){
    int l = i >> 8, n = i & 255;
    bp[l * 1024 + 0   + n] = bq[i];
    bp[l * 1024 + 256 + n] = bk[i];
    bp[l * 1024 + 512 + n] = bv[i];
    bp[l * 1024 + 768 + n] = bs[i];
  }
}

// ---------------- pack Wqe[l][c][j] = sum_d Wq[l][c][d]*We[l][j][d]; bqe --------
__global__ __launch_bounds__(256) void pack_wqe_kernel(
    const float* __restrict__ Wq, const float* __restrict__ We,
    const float* __restrict__ bq, float* __restrict__ Wqe, float* __restrict__ bqe)
{
  __shared__ float We_s[1024];
  int l = blockIdx.x;
  for (int i = threadIdx.x; i < 1024; i += 256) We_s[i] = We[(size_t)l * 1024 + i];
  __syncthreads();
  int k = threadIdx.x;
  const float* wrow = Wq + (size_t)l * 65536 + (size_t)k * 256;
  float s0 = 0.f, s1 = 0.f, s2 = 0.f, s3 = 0.f;
  for (int c = 0; c < 256; c++){
    float wv = wrow[c];
    s0 += wv * We_s[c];
    s1 += wv * We_s[256 + c];
    s2 += wv * We_s[512 + c];
    s3 += wv * We_s[768 + c];
  }
  float4 o; o.x = s0; o.y = s1; o.z = s2; o.w = s3;
  *(float4*)&Wqe[((size_t)l * 256 + k) * 4] = o;
  if (k < 4){
    float b = 0.f;
    for (int c = 0; c < 256; c++) b += bq[l * 256 + c] * We_s[k * 256 + c];
    bqe[l * 4 + k] = b;
  }
}

// ---------------- qwe for conv1 ----------------
__global__ __launch_bounds__(256) void qwe1_kernel(const unsigned short* __restrict__ qkvb,
                                                   const float* __restrict__ We1,
                                                   float* __restrict__ qwe, int N){
  __shared__ float We_s[1024];
  for (int i = threadIdx.x; i < 1024; i += 256) We_s[i] = We1[i];
  __syncthreads();
  int wid = threadIdx.x >> 6, lane = threadIdx.x & 63;
  int n = blockIdx.x * 4 + wid;
  if (n >= N) return;
  int c0 = lane * 4;
  ushort4 qr = *(const ushort4*)&qkvb[(size_t)n * 768 + c0];
  float q0 = b2f(qr.x), q1 = b2f(qr.y), q2 = b2f(qr.z), q3 = b2f(qr.w);
  float4 o;
  #pragma unroll
  for (int j = 0; j < 4; j++){
    float s = q0 * We_s[j * 256 + c0] + q1 * We_s[j * 256 + c0 + 1]
            + q2 * We_s[j * 256 + c0 + 2] + q3 * We_s[j * 256 + c0 + 3];
    s = wred_sum(s);
    if (j == 0) o.x = s; else if (j == 1) o.y = s; else if (j == 2) o.z = s; else o.w = s;
  }
  if (lane == 0) *(float4*)&qwe[(size_t)n * 4] = o;
}

// ---------------- conv1 GEMMs ----------------
__global__ __launch_bounds__(256) void gemm1_kernel(
    const float* __restrict__ A,
    const float* __restrict__ W0, const float* __restrict__ W1,
    const float* __restrict__ W2, const float* __restrict__ W3,
    const float* __restrict__ B0, const float* __restrict__ B1,
    const float* __restrict__ B2, const float* __restrict__ B3,
    unsigned short* __restrict__ qkvb, float* __restrict__ sl, int N)
{
  __shared__ float As[64][16];
  int nb = blockIdx.x * 64;
  {
    int row = nb + (threadIdx.x >> 2);
    int qq = (threadIdx.x & 3) * 4;
    float4 a = make_float4(0.f, 0.f, 0.f, 0.f);
    if (row < N) a = *(const float4*)&A[row * 16 + qq];
    *(float4*)&As[threadIdx.x >> 2][qq] = a;
  }
  __syncthreads();
  int col = threadIdx.x;
  #pragma unroll
  for (int w = 0; w < 4; w++){
    const float* W  = (w == 0) ? W0 : (w == 1) ? W1 : (w == 2) ? W2 : W3;
    const float* Bi = (w == 0) ? B0 : (w == 1) ? B1 : (w == 2) ? B2 : B3;
    float wr[16];
    #pragma unroll
    for (int kk = 0; kk < 16; kk++) wr[kk] = W[kk * 256 + col];
    float bias = Bi[col];
    for (int r = 0; r < 64; r++){
      int row = nb + r;
      if (row >= N) break;
      float acc = bias;
      #pragma unroll
      for (int kk = 0; kk < 16; kk++) acc += As[r][kk] * wr[kk];
      if (w < 3) qkvb[(size_t)row * 768 + w * 256 + col] = f2bf(acc);
      else       sl[(size_t)row * 256 + col] = acc;
    }
  }
}

// ---------------- main MFMA GEMM ----------------
__global__ __launch_bounds__(256, 2) void gemm_mfma_kernel(
    const unsigned short* __restrict__ A,
    const unsigned short* __restrict__ Wp,
    const float* __restrict__ bp,
    unsigned short* __restrict__ qkvb,
    float* __restrict__ sl,
    int M)
{
  __shared__ unsigned short lds[2 * 128 * 64];
  unsigned short* ldsA = lds;
  unsigned short* ldsB = lds + 128 * 64;
  const int tid  = threadIdx.x;
  const int wave = tid >> 6, lane = tid & 63;
  const int wm = wave >> 1, wn = wave & 1;
  const int m0 = blockIdx.x * 128;
  const int n0 = blockIdx.y * 128;

  f32x4 acc[4][4] = {};

  const int srow  = lane >> 3;
  const int sc16  = lane & 7;
  const int skgrp = sc16 ^ (srow & 7);

  for (int k0 = 0; k0 < 256; k0 += 64){
    #pragma unroll
    for (int it = 0; it < 4; ++it){
      int lrow = wave * 32 + it * 8;
      const unsigned short* gA = A + (size_t)(m0 + lrow + srow) * 256 + k0 + skgrp * 8;
      __builtin_amdgcn_global_load_lds((const __attribute__((address_space(1))) unsigned int*)gA,
          (__attribute__((address_space(3))) unsigned int*)(ldsA + lrow * 64), 16, 0, 0);
      const unsigned short* gB = Wp + (size_t)(n0 + lrow + srow) * 256 + k0 + skgrp * 8;
      __builtin_amdgcn_global_load_lds((const __attribute__((address_space(1))) unsigned int*)gB,
          (__attribute__((address_space(3))) unsigned int*)(ldsB + lrow * 64), 16, 0, 0);
    }
    __syncthreads();

    bf16x8 af[4][2], bfr[4][2];
    #pragma unroll
    for (int mb = 0; mb < 4; ++mb){
      int r = wm * 64 + mb * 16 + (lane & 15);
      #pragma unroll
      for (int ks = 0; ks < 2; ++ks){
        int kg = ks * 4 + (lane >> 4);
        af[mb][ks] = *(const bf16x8*)&ldsA[r * 64 + ((kg ^ (r & 7)) * 8)];
      }
    }
    #pragma unroll
    for (int nb = 0; nb < 4; ++nb){
      int r = wn * 64 + nb * 16 + (lane & 15);
      #pragma unroll
      for (int ks = 0; ks < 2; ++ks){
        int kg = ks * 4 + (lane >> 4);
        bfr[nb][ks] = *(const bf16x8*)&ldsB[r * 64 + ((kg ^ (r & 7)) * 8)];
      }
    }
    #pragma unroll
    for (int mb = 0; mb < 4; ++mb){
      #pragma unroll
      for (int nb = 0; nb < 4; ++nb){
        acc[mb][nb] = __builtin_amdgcn_mfma_f32_16x16x32_bf16(af[mb][0], bfr[nb][0], acc[mb][nb], 0, 0, 0);
        acc[mb][nb] = __builtin_amdgcn_mfma_f32_16x16x32_bf16(af[mb][1], bfr[nb][1], acc[mb][nb], 0, 0, 0);
      }
    }
    __syncthreads();
  }

  #pragma unroll
  for (int nb = 0; nb < 4; ++nb){
    int col = n0 + wn * 64 + nb * 16 + (lane & 15);
    float bias = bp[col];
    #pragma unroll
    for (int mb = 0; mb < 4; ++mb){
      #pragma unroll
      for (int r4 = 0; r4 < 4; ++r4){
        int row = m0 + wm * 64 + mb * 16 + (lane >> 4) * 4 + r4;
        if (row < M){
          float o = acc[mb][nb][r4] + bias;
          if (col < 768) qkvb[(size_t)row * 768 + col] = f2bf(o);
          else           sl[(size_t)row * 256 + (col - 768)] = o;
        }
      }
    }
  }
}

// ---------------- edge-parallel alpha: 16 lanes per edge ----------------
__global__ __launch_bounds__(256) void alpha_kernel(
    const unsigned short* __restrict__ qkvb,   // q at 0, k at +256
    const float* __restrict__ qwe,             // [N][4]
    const float* __restrict__ ea,              // [E][4] raw order
    const int* __restrict__ src, const int* __restrict__ dst,
    const int* __restrict__ pos,               // [E] csr slot
    float* __restrict__ alphas, int E)
{
  int e   = (blockIdx.x * 256 + threadIdx.x) >> 4;
  int sub = threadIdx.x & 15;
  if (e >= E) return;
  int s = src[e], d = dst[e];
  const unsigned short* qrow = qkvb + (size_t)d * 768 + sub * 16;
  const unsigned short* krow = qkvb + (size_t)s * 768 + 256 + sub * 16;
  bf16x8 q0 = *(const bf16x8*)qrow;
  bf16x8 q1 = *(const bf16x8*)(qrow + 8);
  bf16x8 k0 = *(const bf16x8*)krow;
  bf16x8 k1 = *(const bf16x8*)(krow + 8);
  float dot = 0.f;
  #pragma unroll
  for (int t = 0; t < 8; t++) dot += b2f((unsigned short)q0[t]) * b2f((unsigned short)k0[t]);
  #pragma unroll
  for (int t = 0; t < 8; t++) dot += b2f((unsigned short)q1[t]) * b2f((unsigned short)k1[t]);
  #pragma unroll
  for (int o = 1; o < 16; o <<= 1) dot += __shfl_xor(dot, o, 64);
  if (sub == 0){
    float4 e4  = *(const float4*)&ea[(size_t)e * 4];
    float4 qw4 = *(const float4*)&qwe[(size_t)d * 4];
    float edot = qw4.x * e4.x + qw4.y * e4.y + qw4.z * e4.z + qw4.w * e4.w;
    alphas[pos[e]] = (dot + edot) * 0.0625f;
  }
}

// ---------------- node aggregation: softmax over precomputed alphas + v gather ----
__global__ __launch_bounds__(256) void agg_kernel(
    const unsigned short* __restrict__ qkvb,   // v at +512
    const float* __restrict__ sl,
    const float* __restrict__ alphas,          // [E] csr order
    const float* __restrict__ ea_csr,          // [E][4] csr order
    const int* __restrict__ src_csr,           // [E] csr order
    const float* __restrict__ We,              // [4][256]
    const float* __restrict__ Wqe_next,        // [256][4] or null
    const float* __restrict__ bqe_next,        // [4] or null
    const int* __restrict__ row_ptr,
    const float* __restrict__ h_in, float* __restrict__ h_out,
    unsigned short* __restrict__ h2b, float* __restrict__ qwe_out,
    int RESID, int N)
{
  int wid = threadIdx.x >> 6, lane = threadIdx.x & 63;
  int n = blockIdx.x * 4 + wid;
  if (n >= N) return;
  int c0 = lane * 4;

  float m = -INFINITY, ssum = 0.f;
  float a0 = 0.f, a1 = 0.f, a2 = 0.f, a3 = 0.f;
  float ec0 = 0.f, ec1 = 0.f, ec2 = 0.f, ec3 = 0.f;
  int e0 = row_ptr[n], e1 = row_ptr[n + 1];

  for (int base = e0; base < e1; base += 64){
    int cnt = min(64, e1 - base);
    float my_alpha = (lane < cnt) ? alphas[base + lane] : -INFINITY;
    float mc = wred_max(my_alpha);
    float mn = fmaxf(m, mc);
    float corr = expf(m - mn);                // m=-inf first window -> 0
    float w = (lane < cnt) ? expf(my_alpha - mn) : 0.f;
    float wsum = wred_sum(w);
    ssum = ssum * corr + wsum;
    a0 *= corr; a1 *= corr; a2 *= corr; a3 *= corr;
    ec0 *= corr; ec1 *= corr; ec2 *= corr; ec3 *= corr;
    m = mn;

    int s_n = src_csr[base];
    ushort4 v_n = *(const ushort4*)&qkvb[(size_t)s_n * 768 + 512 + c0];
    float4 ea_n = *(const float4*)&ea_csr[(size_t)base * 4];
    for (int i = 0; i < cnt; ++i){
      ushort4 vr = v_n; float4 eav = ea_n;
      if (i + 1 < cnt){
        int s2 = src_csr[base + i + 1];
        v_n = *(const ushort4*)&qkvb[(size_t)s2 * 768 + 512 + c0];
        ea_n = *(const float4*)&ea_csr[(size_t)(base + i + 1) * 4];
      }
      float aw = __shfl(w, i, 64);
      a0 += aw * b2f(vr.x);
      a1 += aw * b2f(vr.y);
      a2 += aw * b2f(vr.z);
      a3 += aw * b2f(vr.w);
      ec0 += aw * eav.x;
      ec1 += aw * eav.y;
      ec2 += aw * eav.z;
      ec3 += aw * eav.w;
    }
  }

  float inv = 1.f / (ssum + 1e-16f);
  // emb_c = sum_j ec_j * We[j][c]; coalesced global float4 reads (L1-hot)
  float4 W0 = *(const float4*)&We[0 * 256 + c0];
  float4 W1 = *(const float4*)&We[1 * 256 + c0];
  float4 W2 = *(const float4*)&We[2 * 256 + c0];
  float4 W3 = *(const float4*)&We[3 * 256 + c0];
  float emb0 = ec0 * W0.x + ec1 * W1.x + ec2 * W2.x + ec3 * W3.x;
  float emb1 = ec0 * W0.y + ec1 * W1.y + ec2 * W2.y + ec3 * W3.y;
  float emb2 = ec0 * W0.z + ec1 * W1.z + ec2 * W2.z + ec3 * W3.z;
  float emb3 = ec0 * W0.w + ec1 * W1.w + ec2 * W2.w + ec3 * W3.w;
  float4 slv = *(const float4*)&sl[(size_t)n * 256 + c0];
  float y0 = (a0 + emb0) * inv + slv.x;
  float y1 = (a1 + emb1) * inv + slv.y;
  float y2 = (a2 + emb2) * inv + slv.z;
  float y3 = (a3 + emb3) * inv + slv.w;
  float o0, o1, o2, o3;
  if (RESID){
    float4 hp = *(const float4*)&h_in[(size_t)n * 256 + c0];
    o0 = hp.x + y0; o1 = hp.y + y1; o2 = hp.z + y2; o3 = hp.w + y3;
  } else {
    o0 = y0; o1 = y1; o2 = y2; o3 = y3;
  }
  float4 ho; ho.x = o0; ho.y = o1; ho.z = o2; ho.w = o3;
  *(float4*)&h_out[(size_t)n * 256 + c0] = ho;
  float mean = wred_sum(o0 + o1 + o2 + o3) * (1.f / 256.f);
  float d0 = o0 - mean, d1 = o1 - mean, d2 = o2 - mean, d3 = o3 - mean;
  float var = wred_sum(d0 * d0 + d1 * d1 + d2 * d2 + d3 * d3) * (1.f / 255.f);
  float invstd = 1.f / sqrtf(var);
  float t0 = fmaxf(o0 * invstd, 0.f);
  float t1 = fmaxf(o1 * invstd, 0.f);
  float t2 = fmaxf(o2 * invstd, 0.f);
  float t3 = fmaxf(o3 * invstd, 0.f);
  ushort4 hb;
  hb.x = f2bf(t0); hb.y = f2bf(t1); hb.z = f2bf(t2); hb.w = f2bf(t3);
  *(ushort4*)&h2b[(size_t)n * 256 + c0] = hb;
  // chain: qwe for NEXT layer = h2 @ Wqe_next + bqe_next (coalesced global reads)
  if (Wqe_next){
    float4 g0 = *(const float4*)&Wqe_next[(c0 + 0) * 4];
    float4 g1 = *(const float4*)&Wqe_next[(c0 + 1) * 4];
    float4 g2 = *(const float4*)&Wqe_next[(c0 + 2) * 4];
    float4 g3 = *(const float4*)&Wqe_next[(c0 + 3) * 4];
    float s0 = t0 * g0.x + t1 * g1.x + t2 * g2.x + t3 * g3.x;
    float s1 = t0 * g0.y + t1 * g1.y + t2 * g2.y + t3 * g3.y;
    float s2 = t0 * g0.z + t1 * g1.z + t2 * g2.z + t3 * g3.z;
    float s3 = t0 * g0.w + t1 * g1.w + t2 * g2.w + t3 * g3.w;
    s0 = wred_sum(s0); s1 = wred_sum(s1); s2 = wred_sum(s2); s3 = wred_sum(s3);
    if (lane == 0){
      float4 bq4 = *(const float4*)bqe_next;
      float4 o; o.x = s0 + bq4.x; o.y = s1 + bq4.y; o.z = s2 + bq4.z; o.w = s3 + bq4.w;
      *(float4*)&qwe_out[(size_t)n * 4] = o;
    }
  }
}

// ---------------- output head ----------------
__global__ __launch_bounds__(256) void head_kernel(const float* __restrict__ h,
                                                   const float* __restrict__ wlsc,
                                                   float* __restrict__ out, int N){
  int wid = threadIdx.x >> 6, lane = threadIdx.x & 63;
  int n = blockIdx.x * 4 + wid;
  if (n >= N) return;
  int c0 = lane * 4;
  float4 hv = *(const float4*)&h[(size_t)n * 256 + c0];
  float4 wv = *(const float4*)&wlsc[c0];
  float p = hv.x * wv.x + hv.y * wv.y + hv.z * wv.z + hv.w * wv.w;
  p = wred_sum(p);
  if (lane == 0) out[n] = p * (1.f / sqrtf(15.f)) + wlsc[256];
}

// ---------------- launch ----------------
extern "C" void kernel_launch(void* const* d_in, const int* in_sizes, int n_in,
                              void* d_out, int out_size, void* d_ws, size_t ws_size,
                              hipStream_t stream)
{
  const float* x     = (const float*)d_in[0];
  const int*   eidx  = (const int*)d_in[1];
  const float* Wq1 = (const float*)d_in[3];  const float* bq1 = (const float*)d_in[4];
  const float* Wk1 = (const float*)d_in[5];  const float* bk1 = (const float*)d_in[6];
  const float* Wv1 = (const float*)d_in[7];  const float* bv1 = (const float*)d_in[8];
  const float* We1 = (const float*)d_in[9];
  const float* Ws1 = (const float*)d_in[10]; const float* bs1 = (const float*)d_in[11];
  const float* Wq = (const float*)d_in[12];  const float* bq = (const float*)d_in[13];
  const float* Wk = (const float*)d_in[14];  const float* bk = (const float*)d_in[15];
  const float* Wv = (const float*)d_in[16];  const float* bv = (const float*)d_in[17];
  const float* We = (const float*)d_in[18];
  const float* Ws = (const float*)d_in[19];  const float* bs = (const float*)d_in[20];
  const float* Wl = (const float*)d_in[21];  const float* bl = (const float*)d_in[22];
  const float* scale = (const float*)d_in[23];
  (void)n_in; (void)ws_size;

  int N = in_sizes[0] / 16;
  int E = in_sizes[2] / 4;
  int Mpad = (N + 127) & ~127;
  float* out = (float*)d_out;
  (void)out_size;

  char* p = (char*)d_ws;
  auto alloc = [&](size_t bytes) -> char* {
    char* r = p; p += (bytes + 255) & ~(size_t)255; return r;
  };
  float* hx   = (float*)alloc((size_t)N * 16 * 4);
  float* ea   = (float*)alloc((size_t)E * 4 * 4);
  float* h    = (float*)alloc((size_t)N * 256 * 4);
  unsigned short* h2b = (unsigned short*)alloc((size_t)Mpad * 256 * 2);
  unsigned short* qkvb = (unsigned short*)alloc((size_t)N * 768 * 2);
  float* sl   = (float*)alloc((size_t)N * 256 * 4);
  float* qwe  = (float*)alloc((size_t)N * 4 * 4);
  float* alphas = (float*)alloc((size_t)E * 4);
  float* ea_csr = (float*)alloc((size_t)E * 4 * 4);
  int* src_csr  = (int*)alloc((size_t)E * 4);
  int* pos      = (int*)alloc((size_t)E * 4);
  unsigned short* Wp  = (unsigned short*)alloc((size_t)15 * 1024 * 256 * 2);
  float* bp   = (float*)alloc((size_t)15 * 1024 * 4);
  float* Wqe  = (float*)alloc((size_t)15 * 256 * 4 * 4);
  float* bqe  = (float*)alloc((size_t)15 * 4 * 4);
  float* wlsc = (float*)alloc(257 * 4);
  int* counts  = (int*)alloc((size_t)N * 4);
  int* cursor  = (int*)alloc((size_t)N * 4);
  int* row_ptr = (int*)alloc(((size_t)N + 1) * 4);

  const int* srcp = eidx;
  const int* dstp = eidx + E;

  int nx = N * 16, ne = E * 4;
  int big = nx > ne ? nx : ne;

  zero_kernel<<<(N + 255) / 256, 256, 0, stream>>>(counts, N);
  prep_kernel<<<(big + 255) / 256, 256, 0, stream>>>(x, (const float*)d_in[2], hx, ea, nx, ne);
  hist_kernel<<<(E + 255) / 256, 256, 0, stream>>>(dstp, counts, E);
  scan_kernel<<<1, 1024, 0, stream>>>(counts, row_ptr, cursor, N);
  scatter_kernel<<<(E + 255) / 256, 256, 0, stream>>>(srcp, dstp, ea, cursor, pos,
                                                      src_csr, ea_csr, E);
  wlscale_kernel<<<1, 256, 0, stream>>>(Wl, bl, scale, wlsc);
  pack_w_kernel<<<dim3(8, 32, 15), 256, 0, stream>>>(Wq, Wk, Wv, Ws, Wp);
  pack_b_kernel<<<15, 256, 0, stream>>>(bq, bk, bv, bs, bp);
  pack_wqe_kernel<<<15, 256, 0, stream>>>(Wq, We, bq, Wqe, bqe);

  int ablocks = (E + 15) / 16;

  // conv1
  gemm1_kernel<<<(N + 63) / 64, 256, 0, stream>>>(hx, Wq1, Wk1, Wv1, Ws1,
                                                  bq1, bk1, bv1, bs1, qkvb, sl, N);
  qwe1_kernel<<<(N + 3) / 4, 256, 0, stream>>>(qkvb, We1, qwe, N);
  alpha_kernel<<<ablocks, 256, 0, stream>>>(qkvb, qwe, ea, srcp, dstp, pos, alphas, E);
  agg_kernel<<<(N + 3) / 4, 256, 0, stream>>>(qkvb, sl, alphas, ea_csr, src_csr, We1,
                                              Wqe, bqe, row_ptr,
                                              h, h, h2b, qwe, 0, N);

  // 15 residual blocks
  for (int l = 0; l < 15; l++){
    gemm_mfma_kernel<<<dim3(Mpad / 128, 8), 256, 0, stream>>>(
        h2b, Wp + (size_t)l * 262144, bp + (size_t)l * 1024, qkvb, sl, N);
    alpha_kernel<<<ablocks, 256, 0, stream>>>(qkvb, qwe, ea, srcp, dstp, pos, alphas, E);
    const float* wqe_n = (l < 14) ? (Wqe + (size_t)(l + 1) * 1024) : nullptr;
    const float* bqe_n = (l < 14) ? (bqe + (size_t)(l + 1) * 4) : nullptr;
    agg_kernel<<<(N + 3) / 4, 256, 0, stream>>>(qkvb, sl, alphas, ea_csr, src_csr,
                                                We + (size_t)l * 1024,
                                                wqe_n, bqe_n, row_ptr,
                                                h, h, h2b, qwe, 1, N);
  }

  head_kernel<<<(N + 3) / 4, 256, 0, stream>>>(h, wlsc, out, N);
}